// Round 3
// baseline (319.334 us; speedup 1.0000x reference)
//
#include <hip/hip_runtime.h>

// LinearAttentionBlock bf16 MFMA. Attention reassociated: Q@(K'V).
// FFN GEMMs: 256x256 tile, BK=32, 4-buffer LDS pipeline, counted vmcnt(8),
// granule-XOR LDS swizzle (T2), XCD block swizzle (T1), setprio (T5).
// Small GEMMs: m97-style 128x128 kernel (proven in round 2).

#define MROWS 8192
#define DMODEL 1024
#define DK 128
#define DFF 4096

typedef __attribute__((ext_vector_type(8))) __bf16 bf16x8;
typedef __attribute__((ext_vector_type(4))) float f32x4;

#define BAR()    asm volatile("s_barrier" ::: "memory")
#define WAITV(n) asm volatile("s_waitcnt vmcnt(" #n ")" ::: "memory")

__global__ __launch_bounds__(256) void cast_f32_bf16(
    const float* __restrict__ src, __bf16* __restrict__ dst, int n8)
{
    for (int i = blockIdx.x * blockDim.x + threadIdx.x; i < n8;
         i += gridDim.x * blockDim.x) {
        const float4 a = reinterpret_cast<const float4*>(src)[2 * i];
        const float4 b = reinterpret_cast<const float4*>(src)[2 * i + 1];
        bf16x8 o;
        o[0] = (__bf16)a.x; o[1] = (__bf16)a.y; o[2] = (__bf16)a.z; o[3] = (__bf16)a.w;
        o[4] = (__bf16)b.x; o[5] = (__bf16)b.y; o[6] = (__bf16)b.z; o[7] = (__bf16)b.w;
        reinterpret_cast<bf16x8*>(dst)[i] = o;
    }
}

__global__ void pack_bias3(const float* __restrict__ a, const float* __restrict__ b,
                           const float* __restrict__ c, float* __restrict__ o)
{
    const int t = threadIdx.x;
    o[t] = a[t]; o[128 + t] = b[t]; o[256 + t] = c[t];
}

// ---------------------------------------------------------------------------
// 128x128 m97-style GEMM (round-2 proven). DUAL adds a bf16 secondary output.
// ---------------------------------------------------------------------------
template<bool RELU, bool RESID, bool BIAS, bool OUTBF, bool DUAL>
__global__ __launch_bounds__(256) void gemm128(
    const __bf16* __restrict__ A, int lda,
    const __bf16* __restrict__ W,
    const float* __restrict__ bias,
    const float* __restrict__ resid,
    void* __restrict__ Cout, __bf16* __restrict__ Cbf, int ldc, int K)
{
    constexpr int BK = 32;
    __shared__ __bf16 As[128 * BK];
    __shared__ __bf16 Bs[128 * BK];

    const int tid  = threadIdx.x;
    const int lane = tid & 63;
    const int w    = tid >> 6;
    const int wm   = w >> 1;
    const int wn   = w & 1;
    const int fr   = lane & 15;
    const int fq   = lane >> 4;

    const long row0 = (long)blockIdx.y * 128;
    const long col0 = (long)blockIdx.x * 128;

    const int sr = (w << 4) + (lane >> 2);
    const int sc = (lane & 3) << 3;

    const __bf16* gA0 = A + (row0 + sr) * (long)lda + sc;
    const __bf16* gA1 = A + (row0 + 64 + sr) * (long)lda + sc;
    const __bf16* gW0 = W + (col0 + sr) * (long)K + sc;
    const __bf16* gW1 = W + (col0 + 64 + sr) * (long)K + sc;

    __bf16* lA0 = &As[(w << 4) * BK];
    __bf16* lA1 = &As[((w << 4) + 64) * BK];
    __bf16* lB0 = &Bs[(w << 4) * BK];
    __bf16* lB1 = &Bs[((w << 4) + 64) * BK];

    f32x4 acc[4][4] = {};

    for (int k0 = 0; k0 < K; k0 += BK) {
        __builtin_amdgcn_global_load_lds(
            (const __attribute__((address_space(1))) void*)(gA0 + k0),
            (__attribute__((address_space(3))) void*)lA0, 16, 0, 0);
        __builtin_amdgcn_global_load_lds(
            (const __attribute__((address_space(1))) void*)(gA1 + k0),
            (__attribute__((address_space(3))) void*)lA1, 16, 0, 0);
        __builtin_amdgcn_global_load_lds(
            (const __attribute__((address_space(1))) void*)(gW0 + k0),
            (__attribute__((address_space(3))) void*)lB0, 16, 0, 0);
        __builtin_amdgcn_global_load_lds(
            (const __attribute__((address_space(1))) void*)(gW1 + k0),
            (__attribute__((address_space(3))) void*)lB1, 16, 0, 0);
        __syncthreads();

        bf16x8 af[4], bfr[4];
        #pragma unroll
        for (int m = 0; m < 4; m++)
            af[m] = *reinterpret_cast<const bf16x8*>(
                &As[(wm * 64 + m * 16 + fr) * BK + fq * 8]);
        #pragma unroll
        for (int n = 0; n < 4; n++)
            bfr[n] = *reinterpret_cast<const bf16x8*>(
                &Bs[(wn * 64 + n * 16 + fr) * BK + fq * 8]);

        #pragma unroll
        for (int m = 0; m < 4; m++)
            #pragma unroll
            for (int n = 0; n < 4; n++)
                acc[m][n] = __builtin_amdgcn_mfma_f32_16x16x32_bf16(
                    af[m], bfr[n], acc[m][n], 0, 0, 0);
        __syncthreads();
    }

    #pragma unroll
    for (int n = 0; n < 4; n++) {
        const long c = col0 + wn * 64 + n * 16 + fr;
        float bc = 0.0f;
        if constexpr (BIAS) bc = bias[c];
        #pragma unroll
        for (int m = 0; m < 4; m++) {
            #pragma unroll
            for (int j = 0; j < 4; j++) {
                const long r = row0 + wm * 64 + m * 16 + fq * 4 + j;
                float v = acc[m][n][j];
                if constexpr (BIAS)  v += bc;
                if constexpr (RESID) v += resid[r * ldc + c];
                if constexpr (RELU)  v = fmaxf(v, 0.0f);
                if constexpr (OUTBF) ((__bf16*)Cout)[r * ldc + c] = (__bf16)v;
                else                 ((float*)Cout)[r * ldc + c] = v;
                if constexpr (DUAL)  Cbf[r * ldc + c] = (__bf16)v;
            }
        }
    }
}

// ---------------------------------------------------------------------------
// 256x256 pipelined GEMM. 512 threads = 8 waves (2Mx4N), per-wave 128x64 out.
// BK=32, 4 LDS buffers (A,B each 4x16KB = 128 KiB total).
// Tile t computes from buf[t&3] while staging tile t+3 into buf[(t+3)&3];
// boundary: counted vmcnt (8 / 4 / 0 peel), raw s_barrier (no full drain).
// LDS swizzle: 16B-granule pg = g ^ (row&3); global source pre-swizzled,
// linear global_load_lds dest, swizzled ds_read (rule #21).
// Requires: M%256==0, N%256==0, K%32==0, K/32>=3, grid=1D with nwg%8==0.
// ---------------------------------------------------------------------------
template<bool RELU, bool RESID, bool BIAS, bool OUTBF>
__global__ __launch_bounds__(512) void gemm256(
    const __bf16* __restrict__ A, int lda,
    const __bf16* __restrict__ W,
    const float* __restrict__ bias,
    const float* __restrict__ resid,
    void* __restrict__ Cout, int ldc, int K, int nbx)
{
    constexpr int BK = 32;
    __shared__ __bf16 sA[4][256 * BK];   // 4 x 16 KB
    __shared__ __bf16 sB[4][256 * BK];   // 4 x 16 KB

    // XCD-aware bijective swizzle (nwg % 8 == 0)
    const int nwg   = gridDim.x;
    const int bid   = blockIdx.x;
    const int chunk = nwg >> 3;
    const int swz   = (bid & 7) * chunk + (bid >> 3);
    const int bx    = swz % nbx;
    const int by    = swz / nbx;

    const long row0 = (long)by * 256;
    const long col0 = (long)bx * 256;

    const int tid  = threadIdx.x;
    const int lane = tid & 63;
    const int w    = tid >> 6;    // wave 0..7
    const int wm   = w >> 2;      // 0..1
    const int wn   = w & 3;       // 0..3
    const int fr   = lane & 15;
    const int fq   = lane >> 4;   // 0..3

    // staging: phys row = i*128 + w*16 + (lane>>2), phys granule = lane&3.
    // logical granule = pg ^ (row&3) -> pre-swizzled source column.
    const int srow = (w << 4) + (lane >> 2);
    const int scol = (((lane & 3) ^ ((lane >> 2) & 3)) << 3);
    const __bf16* gA = A + (row0 + srow) * (long)lda + scol;
    const __bf16* gW = W + (col0 + srow) * (long)K + scol;

    // ds_read byte offsets: logical (R, G=fq) at phys R*64 + (fq^(R&3))*16
    const int swzg = (fq ^ (fr & 3)) << 4;
    const int rdA  = ((wm * 128 + fr) << 6) + swzg;   // + m*1024
    const int rdB  = ((wn * 64  + fr) << 6) + swzg;   // + n*1024

    auto stageA = [&](int b, int t) {
        const __bf16* s = gA + (long)t * BK;
        char* d = (char*)(&sA[b][0]) + (w << 10);
        __builtin_amdgcn_global_load_lds(
            (const __attribute__((address_space(1))) void*)s,
            (__attribute__((address_space(3))) void*)d, 16, 0, 0);
        __builtin_amdgcn_global_load_lds(
            (const __attribute__((address_space(1))) void*)(s + 128 * (long)lda),
            (__attribute__((address_space(3))) void*)(d + 8192), 16, 0, 0);
    };
    auto stageB = [&](int b, int t) {
        const __bf16* s = gW + (long)t * BK;
        char* d = (char*)(&sB[b][0]) + (w << 10);
        __builtin_amdgcn_global_load_lds(
            (const __attribute__((address_space(1))) void*)s,
            (__attribute__((address_space(3))) void*)d, 16, 0, 0);
        __builtin_amdgcn_global_load_lds(
            (const __attribute__((address_space(1))) void*)(s + 128 * (long)K),
            (__attribute__((address_space(3))) void*)(d + 8192), 16, 0, 0);
    };

    const int nt = K >> 5;           // K/32, >= 3 required
    f32x4 acc[8][4] = {};

    // prologue: stage tiles 0,1,2; wait tile0 (8 = tiles 1,2 in flight)
    stageA(0, 0); stageB(0, 0);
    stageA(1, 1); stageB(1, 1);
    stageA(2, 2); stageB(2, 2);
    WAITV(8);
    BAR();

    for (int t = 0; t < nt; ++t) {
        const int b = t & 3;
        const char* pA = (const char*)(&sA[b][0]);
        const char* pB = (const char*)(&sB[b][0]);

        // ---------------- phase 1: m-frags 0-3 x n-frags 0-3
        bf16x8 a[4], bb[4];
        #pragma unroll
        for (int m = 0; m < 4; m++)
            a[m] = *reinterpret_cast<const bf16x8*>(pA + rdA + (m << 10));
        #pragma unroll
        for (int n = 0; n < 4; n++)
            bb[n] = *reinterpret_cast<const bf16x8*>(pB + rdB + (n << 10));
        if (t + 3 < nt) stageA((t + 3) & 3, t + 3);
        BAR();
        __builtin_amdgcn_s_setprio(1);
        #pragma unroll
        for (int m = 0; m < 4; m++)
            #pragma unroll
            for (int n = 0; n < 4; n++)
                acc[m][n] = __builtin_amdgcn_mfma_f32_16x16x32_bf16(
                    a[m], bb[n], acc[m][n], 0, 0, 0);
        __builtin_amdgcn_s_setprio(0);
        BAR();

        // ---------------- phase 2: m-frags 4-7 x n-frags 0-3
        bf16x8 a2[4];
        #pragma unroll
        for (int m = 0; m < 4; m++)
            a2[m] = *reinterpret_cast<const bf16x8*>(pA + rdA + ((m + 4) << 10));
        if (t + 3 < nt) stageB((t + 3) & 3, t + 3);
        BAR();
        __builtin_amdgcn_s_setprio(1);
        #pragma unroll
        for (int m = 0; m < 4; m++)
            #pragma unroll
            for (int n = 0; n < 4; n++)
                acc[m + 4][n] = __builtin_amdgcn_mfma_f32_16x16x32_bf16(
                    a2[m], bb[n], acc[m + 4][n], 0, 0, 0);
        __builtin_amdgcn_s_setprio(0);

        // ---------------- boundary: tile t+1's loads must have landed
        if (t + 3 < nt)      { WAITV(8); }
        else if (t + 2 < nt) { WAITV(4); }
        else if (t + 1 < nt) { WAITV(0); }
        BAR();
    }

    // epilogue
    #pragma unroll
    for (int n = 0; n < 4; n++) {
        const long c = col0 + wn * 64 + n * 16 + fr;
        float bc = 0.0f;
        if constexpr (BIAS) bc = bias[c];
        #pragma unroll
        for (int m = 0; m < 8; m++) {
            #pragma unroll
            for (int j = 0; j < 4; j++) {
                const long r = row0 + wm * 128 + m * 16 + fq * 4 + j;
                float v = acc[m][n][j];
                if constexpr (BIAS)  v += bc;
                if constexpr (RESID) v += resid[r * ldc + c];
                if constexpr (RELU)  v = fmaxf(v, 0.0f);
                if constexpr (OUTBF) ((__bf16*)Cout)[r * ldc + c] = (__bf16)v;
                else                 ((float*)Cout)[r * ldc + c] = v;
            }
        }
    }
}

// ---------------------------------------------------------------------------
// K^T @ V partials + reduce (unchanged, round-2 proven)
// ---------------------------------------------------------------------------
__global__ __launch_bounds__(256) void ktv_partial(
    const __bf16* __restrict__ Kp, const __bf16* __restrict__ Vp,
    int ld, float* __restrict__ part)
{
    __shared__ float ks[32][DK];
    __shared__ float vs[32][DK];
    const int tid = threadIdx.x;
    const int ti  = tid >> 4;
    const int tj  = tid & 15;
    float acc[8][8] = {};
    const long base = (long)blockIdx.x * 128;

    for (int n0 = 0; n0 < 128; n0 += 32) {
        for (int t = tid; t < 512; t += 256) {
            const int r  = t >> 4;
            const int cc = (t & 15) << 3;
            const bf16x8 k8 = *reinterpret_cast<const bf16x8*>(
                &Kp[(base + n0 + r) * (long)ld + cc]);
            const bf16x8 v8 = *reinterpret_cast<const bf16x8*>(
                &Vp[(base + n0 + r) * (long)ld + cc]);
            #pragma unroll
            for (int u = 0; u < 8; u++) {
                ks[r][cc + u] = (float)k8[u];
                vs[r][cc + u] = (float)v8[u];
            }
        }
        __syncthreads();
        for (int n = 0; n < 32; n++) {
            float kk[8], vv[8];
            #pragma unroll
            for (int i = 0; i < 8; i++) kk[i] = ks[n][(ti << 3) + i];
            #pragma unroll
            for (int j = 0; j < 8; j++) vv[j] = vs[n][(tj << 3) + j];
            #pragma unroll
            for (int i = 0; i < 8; i++)
                #pragma unroll
                for (int j = 0; j < 8; j++)
                    acc[i][j] = fmaf(kk[i], vv[j], acc[i][j]);
        }
        __syncthreads();
    }

    float* dst = &part[(long)blockIdx.x * (DK * DK)];
    #pragma unroll
    for (int i = 0; i < 8; i++) {
        const int ig = (ti << 3) + i;
        *reinterpret_cast<float4*>(&dst[ig * DK + (tj << 3)]) =
            make_float4(acc[i][0], acc[i][1], acc[i][2], acc[i][3]);
        *reinterpret_cast<float4*>(&dst[ig * DK + (tj << 3) + 4]) =
            make_float4(acc[i][4], acc[i][5], acc[i][6], acc[i][7]);
    }
}

__global__ __launch_bounds__(256) void ktv_reduce(
    const float* __restrict__ part, __bf16* __restrict__ ktvT)
{
    const int t = blockIdx.x * 256 + threadIdx.x;
    const int i = t >> 7;
    const int j = t & 127;
    float s = 0.0f;
    for (int b = 0; b < 64; b++) s += part[(long)b * (DK * DK) + t];
    ktvT[j * DK + i] = (__bf16)s;
}

// ---------------------------------------------------------------------------
extern "C" void kernel_launch(void* const* d_in, const int* in_sizes, int n_in,
                              void* d_out, int out_size, void* d_ws, size_t ws_size,
                              hipStream_t stream) {
    const float* x  = (const float*)d_in[0];
    const float* Wq = (const float*)d_in[1];
    const float* bq = (const float*)d_in[2];
    const float* Wk = (const float*)d_in[3];
    const float* bk = (const float*)d_in[4];
    const float* Wv = (const float*)d_in[5];
    const float* bv = (const float*)d_in[6];
    const float* Wp = (const float*)d_in[7];
    const float* bp = (const float*)d_in[8];
    const float* W1 = (const float*)d_in[9];
    const float* b1 = (const float*)d_in[10];
    const float* W2 = (const float*)d_in[11];
    const float* b2 = (const float*)d_in[12];
    float* out = (float*)d_out;

    char* ws = (char*)d_ws;
    const size_t MB = 1ull << 20;
    __bf16* xb    = (__bf16*)(ws);              // 16.8 MB
    __bf16* x2b   = (__bf16*)(ws +  17 * MB);   // 16.8 MB
    __bf16* Hb    = (__bf16*)(ws +  34 * MB);   // 67.1 MB
    __bf16* QKVb  = (__bf16*)(ws + 102 * MB);   //  6.3 MB [8192][384]
    __bf16* W1b   = (__bf16*)(ws + 109 * MB);   //  8.4 MB
    __bf16* W2b   = (__bf16*)(ws + 118 * MB);   //  8.4 MB
    __bf16* Wqkvb = (__bf16*)(ws + 127 * MB);   //  0.8 MB [384][1024]
    __bf16* Wpb   = (__bf16*)(ws + 128 * MB);   //  0.3 MB
    float*  Part  = (float*) (ws + 129 * MB);   //  4.2 MB
    __bf16* KtvTb = (__bf16*)(ws + 134 * MB);   //  32 KB
    __bf16* Ctxb  = (__bf16*)(ws + 135 * MB);   //  2.1 MB
    float*  bqkvf = (float*) (ws + 138 * MB);   //  1.5 KB

    const dim3 blk(256);

    // casts
    cast_f32_bf16<<<2048, blk, 0, stream>>>(x,  xb,           MROWS * DMODEL / 8);
    cast_f32_bf16<<<64,   blk, 0, stream>>>(Wq, Wqkvb,        DK * DMODEL / 8);
    cast_f32_bf16<<<64,   blk, 0, stream>>>(Wk, Wqkvb + DK * DMODEL,     DK * DMODEL / 8);
    cast_f32_bf16<<<64,   blk, 0, stream>>>(Wv, Wqkvb + 2 * DK * DMODEL, DK * DMODEL / 8);
    cast_f32_bf16<<<64,   blk, 0, stream>>>(Wp, Wpb,          DMODEL * DK / 8);
    cast_f32_bf16<<<1024, blk, 0, stream>>>(W1, W1b,          DFF * DMODEL / 8);
    cast_f32_bf16<<<1024, blk, 0, stream>>>(W2, W2b,          DMODEL * DFF / 8);
    pack_bias3<<<1, 128, 0, stream>>>(bq, bk, bv, bqkvf);

    // QKV packed projection -> bf16 [8192,384]
    gemm128<false,false,true,true,false><<<dim3(3, 64), blk, 0, stream>>>(
        xb, DMODEL, Wqkvb, bqkvf, nullptr, QKVb, nullptr, 3 * DK, DMODEL);

    // KtV (128x128) -> transposed bf16
    ktv_partial<<<64, blk, 0, stream>>>(QKVb + DK, QKVb + 2 * DK, 3 * DK, Part);
    ktv_reduce <<<64, blk, 0, stream>>>(Part, KtvTb);

    // context = Q @ KtV -> bf16 [8192,128]
    gemm128<false,false,false,true,false><<<dim3(1, 64), blk, 0, stream>>>(
        QKVb, 3 * DK, KtvTb, nullptr, nullptr, Ctxb, nullptr, DK, DK);

    // x2 = x + ctx @ Wp^T + bp -> fp32 d_out AND bf16 x2b (fused cast)
    gemm128<false,true,true,false,true><<<dim3(8, 64), blk, 0, stream>>>(
        Ctxb, DK, Wpb, bp, x, out, x2b, DMODEL, DK);

    // h = relu(x2 @ W1^T + b1) -> bf16 [8192,4096]; grid 16x32=512 blocks
    gemm256<true,false,true,true><<<512, 512, 0, stream>>>(
        x2b, DMODEL, W1b, b1, nullptr, Hb, DFF, DMODEL, DFF / 256);

    // y = x2 + h @ W2^T + b2 -> fp32 d_out; grid 4x32=128 blocks
    gemm256<false,true,true,false><<<128, 512, 0, stream>>>(
        Hb, DFF, W2b, b2, out, out, DMODEL, DFF, DMODEL / 256);
}

// Round 4
// 295.928 us; speedup vs baseline: 1.0791x; 1.0791x over previous
//
#include <hip/hip_runtime.h>

// LinearAttentionBlock bf16 MFMA. Attention reassociated: Q@(K'V).
// FFN GEMMs: faithful m201 8-phase 256x256/BK=64 template (plain HIP):
//   - 1 half-tile (128x64) staged per phase, 7 ahead, counted vmcnt(6),
//   - per-phase {ds_read || global_load_lds -> bar -> setprio MFMA -> bar},
//   - T2 swizzle byte ^= ((row&7)<<4) via pre-swizzled global source,
//   - T1 XCD-chunked block swizzle.
// Small GEMMs: m97-style 128x128 kernel (round-2 proven).

#define MROWS 8192
#define DMODEL 1024
#define DK 128
#define DFF 4096

typedef __attribute__((ext_vector_type(8))) __bf16 bf16x8;
typedef __attribute__((ext_vector_type(4))) float f32x4;

#define BAR()    asm volatile("s_barrier" ::: "memory")
#define WAITV(n) asm volatile("s_waitcnt vmcnt(" #n ")" ::: "memory")
#define GLOAD(src, dst) __builtin_amdgcn_global_load_lds( \
    (const __attribute__((address_space(1))) void*)(src), \
    (__attribute__((address_space(3))) void*)(dst), 16, 0, 0)

__global__ __launch_bounds__(256) void cast_f32_bf16(
    const float* __restrict__ src, __bf16* __restrict__ dst, int n8)
{
    for (int i = blockIdx.x * blockDim.x + threadIdx.x; i < n8;
         i += gridDim.x * blockDim.x) {
        const float4 a = reinterpret_cast<const float4*>(src)[2 * i];
        const float4 b = reinterpret_cast<const float4*>(src)[2 * i + 1];
        bf16x8 o;
        o[0] = (__bf16)a.x; o[1] = (__bf16)a.y; o[2] = (__bf16)a.z; o[3] = (__bf16)a.w;
        o[4] = (__bf16)b.x; o[5] = (__bf16)b.y; o[6] = (__bf16)b.z; o[7] = (__bf16)b.w;
        reinterpret_cast<bf16x8*>(dst)[i] = o;
    }
}

__global__ void pack_bias3(const float* __restrict__ a, const float* __restrict__ b,
                           const float* __restrict__ c, float* __restrict__ o)
{
    const int t = threadIdx.x;
    o[t] = a[t]; o[128 + t] = b[t]; o[256 + t] = c[t];
}

// ---------------------------------------------------------------------------
// 128x128 m97-style GEMM (round-2 proven). DUAL adds a bf16 secondary output.
// ---------------------------------------------------------------------------
template<bool RELU, bool RESID, bool BIAS, bool OUTBF, bool DUAL>
__global__ __launch_bounds__(256) void gemm128(
    const __bf16* __restrict__ A, int lda,
    const __bf16* __restrict__ W,
    const float* __restrict__ bias,
    const float* __restrict__ resid,
    void* __restrict__ Cout, __bf16* __restrict__ Cbf, int ldc, int K)
{
    constexpr int BK = 32;
    __shared__ __bf16 As[128 * BK];
    __shared__ __bf16 Bs[128 * BK];

    const int tid  = threadIdx.x;
    const int lane = tid & 63;
    const int w    = tid >> 6;
    const int wm   = w >> 1;
    const int wn   = w & 1;
    const int fr   = lane & 15;
    const int fq   = lane >> 4;

    const long row0 = (long)blockIdx.y * 128;
    const long col0 = (long)blockIdx.x * 128;

    const int sr = (w << 4) + (lane >> 2);
    const int sc = (lane & 3) << 3;

    const __bf16* gA0 = A + (row0 + sr) * (long)lda + sc;
    const __bf16* gA1 = A + (row0 + 64 + sr) * (long)lda + sc;
    const __bf16* gW0 = W + (col0 + sr) * (long)K + sc;
    const __bf16* gW1 = W + (col0 + 64 + sr) * (long)K + sc;

    __bf16* lA0 = &As[(w << 4) * BK];
    __bf16* lA1 = &As[((w << 4) + 64) * BK];
    __bf16* lB0 = &Bs[(w << 4) * BK];
    __bf16* lB1 = &Bs[((w << 4) + 64) * BK];

    f32x4 acc[4][4] = {};

    for (int k0 = 0; k0 < K; k0 += BK) {
        GLOAD(gA0 + k0, lA0);
        GLOAD(gA1 + k0, lA1);
        GLOAD(gW0 + k0, lB0);
        GLOAD(gW1 + k0, lB1);
        __syncthreads();

        bf16x8 af[4], bfr[4];
        #pragma unroll
        for (int m = 0; m < 4; m++)
            af[m] = *reinterpret_cast<const bf16x8*>(
                &As[(wm * 64 + m * 16 + fr) * BK + fq * 8]);
        #pragma unroll
        for (int n = 0; n < 4; n++)
            bfr[n] = *reinterpret_cast<const bf16x8*>(
                &Bs[(wn * 64 + n * 16 + fr) * BK + fq * 8]);

        #pragma unroll
        for (int m = 0; m < 4; m++)
            #pragma unroll
            for (int n = 0; n < 4; n++)
                acc[m][n] = __builtin_amdgcn_mfma_f32_16x16x32_bf16(
                    af[m], bfr[n], acc[m][n], 0, 0, 0);
        __syncthreads();
    }

    #pragma unroll
    for (int n = 0; n < 4; n++) {
        const long c = col0 + wn * 64 + n * 16 + fr;
        float bc = 0.0f;
        if constexpr (BIAS) bc = bias[c];
        #pragma unroll
        for (int m = 0; m < 4; m++) {
            #pragma unroll
            for (int j = 0; j < 4; j++) {
                const long r = row0 + wm * 64 + m * 16 + fq * 4 + j;
                float v = acc[m][n][j];
                if constexpr (BIAS)  v += bc;
                if constexpr (RESID) v += resid[r * ldc + c];
                if constexpr (RELU)  v = fmaxf(v, 0.0f);
                if constexpr (OUTBF) ((__bf16*)Cout)[r * ldc + c] = (__bf16)v;
                else                 ((float*)Cout)[r * ldc + c] = v;
                if constexpr (DUAL)  Cbf[r * ldc + c] = (__bf16)v;
            }
        }
    }
}

// ---------------------------------------------------------------------------
// m201-style 8-phase 256x256 GEMM, BK=64, 512 threads = 8 waves (2M x 4N),
// per-wave 128x64 out. LDS = 8 half-slots x 16KB = 128 KiB
// (slot(u&1, j): j 0=B0,1=B1,2=A0,3=A1). Stage 7 half-tiles ahead; per tile t
// phases stage [t+1.A1, t+2.B0, t+2.B1, t+2.A0]; boundary vmcnt(6) (tail 0).
// Swizzle: byte ^= ((row&7)<<4); source pre-swizzled col ((lane&7)^(lane>>3))*8.
// Requires: M%256==0, N%256==0, K%64==0, K/64>=2, grid 1D nwg%8==0.
// ---------------------------------------------------------------------------
template<bool RELU, bool RESID, bool BIAS, bool OUTBF>
__global__ __launch_bounds__(512, 2) void gemm256p(
    const __bf16* __restrict__ A, int lda,
    const __bf16* __restrict__ W,
    const float* __restrict__ bias,
    const float* __restrict__ resid,
    void* __restrict__ Cout, int ldc, int K, int nbx)
{
    __shared__ char lds[8][16384];

    // T1: XCD-chunked bijective swizzle (nwg % 8 == 0)
    const int nwg   = gridDim.x;
    const int bid   = blockIdx.x;
    const int chunk = nwg >> 3;
    const int swz   = (bid & 7) * chunk + (bid >> 3);
    const int bx    = swz % nbx;
    const int by    = swz / nbx;

    const long row0 = (long)by * 256;
    const long col0 = (long)bx * 256;

    const int tid  = threadIdx.x;
    const int lane = tid & 63;
    const int w    = tid >> 6;    // wave 0..7
    const int wm   = w >> 2;      // 0..1  -> A-half
    const int wn   = w & 3;       // 0..3  -> B-half wn>>1, sub-half wn&1
    const int fr   = lane & 15;
    const int fq   = lane >> 4;   // 0..3

    // ---- staging source (pre-swizzled col), rows l*64 + w*8 + (lane>>3)
    const int srow8 = lane >> 3;                    // 0..7
    const int scole = ((lane & 7) ^ srow8) << 3;    // source col elems
    const __bf16* gA = A + (row0 + w * 8 + srow8) * (long)lda + scole;
    const __bf16* gB = W + (col0 + w * 8 + srow8) * (long)K + scole;

    char* ldsc = &lds[0][0];
    const int nt = K >> 6;

    // stage half-tile j of K-tile u (j: 0=B0,1=B1,2=A0,3=A1); 2 loads/thread
    auto stage = [&](int u, int j) {
        if (u >= nt) return;
        char* dst = ldsc + (((u & 1) << 2 | j) << 14) + (w << 10);
        if (j < 2) {
            const __bf16* s = gB + ((long)j * 128) * (long)K + (long)u * 64;
            GLOAD(s, dst);
            GLOAD(s + 64 * (long)K, dst + 8192);
        } else {
            const __bf16* s = gA + ((long)(j - 2) * 128) * (long)lda + (long)u * 64;
            GLOAD(s, dst);
            GLOAD(s + 64 * (long)lda, dst + 8192);
        }
    };

    // ---- reader lane bases (within a half-slot), T2 swizzle on bits 4-6
    const int rb0 = fr * 128 + ((fq * 16) ^ ((fr & 7) << 4));        // ks=0
    const int rb1 = fr * 128 + (((64 + fq * 16)) ^ ((fr & 7) << 4)); // ks=1

    f32x4 acc[8][4] = {};

    // ---- prologue: stage tile0 (B0,B1,A0,A1) + tile1 (B0,B1,A0) = 7 halves
    stage(0, 0); stage(0, 1); stage(0, 2); stage(0, 3);
    stage(1, 0); stage(1, 1); stage(1, 2);
    WAITV(6);
    BAR();

    for (int t = 0; t < nt; ++t) {
        const char* base = ldsc + ((t & 1) << 16);
        const char* pB = base + ((wn >> 1) << 14) + ((wn & 1) << 13);
        const char* pA = base + ((2 + wm) << 14);

        bf16x8 a[8][2], bb[4][2];

        // ---------- phase 0: read B (8) + A m0-1 (4); MFMA m0,m1
        #pragma unroll
        for (int n = 0; n < 4; n++) {
            bb[n][0] = *reinterpret_cast<const bf16x8*>(pB + rb0 + n * 2048);
            bb[n][1] = *reinterpret_cast<const bf16x8*>(pB + rb1 + n * 2048);
        }
        #pragma unroll
        for (int m = 0; m < 2; m++) {
            a[m][0] = *reinterpret_cast<const bf16x8*>(pA + rb0 + m * 2048);
            a[m][1] = *reinterpret_cast<const bf16x8*>(pA + rb1 + m * 2048);
        }
        stage(t + 1, 3);
        BAR();
        __builtin_amdgcn_s_setprio(1);
        #pragma unroll
        for (int m = 0; m < 2; m++)
            #pragma unroll
            for (int n = 0; n < 4; n++) {
                acc[m][n] = __builtin_amdgcn_mfma_f32_16x16x32_bf16(
                    a[m][0], bb[n][0], acc[m][n], 0, 0, 0);
                acc[m][n] = __builtin_amdgcn_mfma_f32_16x16x32_bf16(
                    a[m][1], bb[n][1], acc[m][n], 0, 0, 0);
            }
        __builtin_amdgcn_s_setprio(0);
        BAR();

        // ---------- phase 1: read A m2-5 (8); MFMA m2,m3
        #pragma unroll
        for (int m = 2; m < 6; m++) {
            a[m][0] = *reinterpret_cast<const bf16x8*>(pA + rb0 + m * 2048);
            a[m][1] = *reinterpret_cast<const bf16x8*>(pA + rb1 + m * 2048);
        }
        stage(t + 2, 0);
        BAR();
        __builtin_amdgcn_s_setprio(1);
        #pragma unroll
        for (int m = 2; m < 4; m++)
            #pragma unroll
            for (int n = 0; n < 4; n++) {
                acc[m][n] = __builtin_amdgcn_mfma_f32_16x16x32_bf16(
                    a[m][0], bb[n][0], acc[m][n], 0, 0, 0);
                acc[m][n] = __builtin_amdgcn_mfma_f32_16x16x32_bf16(
                    a[m][1], bb[n][1], acc[m][n], 0, 0, 0);
            }
        __builtin_amdgcn_s_setprio(0);
        BAR();

        // ---------- phase 2: read A m6-7 (4); MFMA m4,m5
        #pragma unroll
        for (int m = 6; m < 8; m++) {
            a[m][0] = *reinterpret_cast<const bf16x8*>(pA + rb0 + m * 2048);
            a[m][1] = *reinterpret_cast<const bf16x8*>(pA + rb1 + m * 2048);
        }
        stage(t + 2, 1);
        BAR();
        __builtin_amdgcn_s_setprio(1);
        #pragma unroll
        for (int m = 4; m < 6; m++)
            #pragma unroll
            for (int n = 0; n < 4; n++) {
                acc[m][n] = __builtin_amdgcn_mfma_f32_16x16x32_bf16(
                    a[m][0], bb[n][0], acc[m][n], 0, 0, 0);
                acc[m][n] = __builtin_amdgcn_mfma_f32_16x16x32_bf16(
                    a[m][1], bb[n][1], acc[m][n], 0, 0, 0);
            }
        __builtin_amdgcn_s_setprio(0);
        BAR();

        // ---------- phase 3: MFMA m6,m7
        stage(t + 2, 2);
        BAR();
        __builtin_amdgcn_s_setprio(1);
        #pragma unroll
        for (int m = 6; m < 8; m++)
            #pragma unroll
            for (int n = 0; n < 4; n++) {
                acc[m][n] = __builtin_amdgcn_mfma_f32_16x16x32_bf16(
                    a[m][0], bb[n][0], acc[m][n], 0, 0, 0);
                acc[m][n] = __builtin_amdgcn_mfma_f32_16x16x32_bf16(
                    a[m][1], bb[n][1], acc[m][n], 0, 0, 0);
            }
        __builtin_amdgcn_s_setprio(0);

        // ---------- boundary: next tile fully landed; never drain mid-loop
        if (t + 2 < nt)      { WAITV(6); }
        else if (t + 1 < nt) { WAITV(0); }
        BAR();
    }

    // epilogue: C/D layout col = lane&15, row = (lane>>4)*4 + reg
    #pragma unroll
    for (int n = 0; n < 4; n++) {
        const long c = col0 + wn * 64 + n * 16 + fr;
        float bc = 0.0f;
        if constexpr (BIAS) bc = bias[c];
        #pragma unroll
        for (int m = 0; m < 8; m++) {
            #pragma unroll
            for (int j = 0; j < 4; j++) {
                const long r = row0 + wm * 128 + m * 16 + fq * 4 + j;
                float v = acc[m][n][j];
                if constexpr (BIAS)  v += bc;
                if constexpr (RESID) v += resid[r * ldc + c];
                if constexpr (RELU)  v = fmaxf(v, 0.0f);
                if constexpr (OUTBF) ((__bf16*)Cout)[r * ldc + c] = (__bf16)v;
                else                 ((float*)Cout)[r * ldc + c] = v;
            }
        }
    }
}

// ---------------------------------------------------------------------------
// K^T @ V partials + reduce (round-2 proven)
// ---------------------------------------------------------------------------
__global__ __launch_bounds__(256) void ktv_partial(
    const __bf16* __restrict__ Kp, const __bf16* __restrict__ Vp,
    int ld, float* __restrict__ part)
{
    __shared__ float ks[32][DK];
    __shared__ float vs[32][DK];
    const int tid = threadIdx.x;
    const int ti  = tid >> 4;
    const int tj  = tid & 15;
    float acc[8][8] = {};
    const long base = (long)blockIdx.x * 128;

    for (int n0 = 0; n0 < 128; n0 += 32) {
        for (int t = tid; t < 512; t += 256) {
            const int r  = t >> 4;
            const int cc = (t & 15) << 3;
            const bf16x8 k8 = *reinterpret_cast<const bf16x8*>(
                &Kp[(base + n0 + r) * (long)ld + cc]);
            const bf16x8 v8 = *reinterpret_cast<const bf16x8*>(
                &Vp[(base + n0 + r) * (long)ld + cc]);
            #pragma unroll
            for (int u = 0; u < 8; u++) {
                ks[r][cc + u] = (float)k8[u];
                vs[r][cc + u] = (float)v8[u];
            }
        }
        __syncthreads();
        for (int n = 0; n < 32; n++) {
            float kk[8], vv[8];
            #pragma unroll
            for (int i = 0; i < 8; i++) kk[i] = ks[n][(ti << 3) + i];
            #pragma unroll
            for (int j = 0; j < 8; j++) vv[j] = vs[n][(tj << 3) + j];
            #pragma unroll
            for (int i = 0; i < 8; i++)
                #pragma unroll
                for (int j = 0; j < 8; j++)
                    acc[i][j] = fmaf(kk[i], vv[j], acc[i][j]);
        }
        __syncthreads();
    }

    float* dst = &part[(long)blockIdx.x * (DK * DK)];
    #pragma unroll
    for (int i = 0; i < 8; i++) {
        const int ig = (ti << 3) + i;
        *reinterpret_cast<float4*>(&dst[ig * DK + (tj << 3)]) =
            make_float4(acc[i][0], acc[i][1], acc[i][2], acc[i][3]);
        *reinterpret_cast<float4*>(&dst[ig * DK + (tj << 3) + 4]) =
            make_float4(acc[i][4], acc[i][5], acc[i][6], acc[i][7]);
    }
}

__global__ __launch_bounds__(256) void ktv_reduce(
    const float* __restrict__ part, __bf16* __restrict__ ktvT)
{
    const int t = blockIdx.x * 256 + threadIdx.x;
    const int i = t >> 7;
    const int j = t & 127;
    float s = 0.0f;
    for (int b = 0; b < 64; b++) s += part[(long)b * (DK * DK) + t];
    ktvT[j * DK + i] = (__bf16)s;
}

// ---------------------------------------------------------------------------
extern "C" void kernel_launch(void* const* d_in, const int* in_sizes, int n_in,
                              void* d_out, int out_size, void* d_ws, size_t ws_size,
                              hipStream_t stream) {
    const float* x  = (const float*)d_in[0];
    const float* Wq = (const float*)d_in[1];
    const float* bq = (const float*)d_in[2];
    const float* Wk = (const float*)d_in[3];
    const float* bk = (const float*)d_in[4];
    const float* Wv = (const float*)d_in[5];
    const float* bv = (const float*)d_in[6];
    const float* Wp = (const float*)d_in[7];
    const float* bp = (const float*)d_in[8];
    const float* W1 = (const float*)d_in[9];
    const float* b1 = (const float*)d_in[10];
    const float* W2 = (const float*)d_in[11];
    const float* b2 = (const float*)d_in[12];
    float* out = (float*)d_out;

    char* ws = (char*)d_ws;
    const size_t MB = 1ull << 20;
    __bf16* xb    = (__bf16*)(ws);              // 16.8 MB
    __bf16* x2b   = (__bf16*)(ws +  17 * MB);   // 16.8 MB
    __bf16* Hb    = (__bf16*)(ws +  34 * MB);   // 67.1 MB
    __bf16* QKVb  = (__bf16*)(ws + 102 * MB);   //  6.3 MB [8192][384]
    __bf16* W1b   = (__bf16*)(ws + 109 * MB);   //  8.4 MB
    __bf16* W2b   = (__bf16*)(ws + 118 * MB);   //  8.4 MB
    __bf16* Wqkvb = (__bf16*)(ws + 127 * MB);   //  0.8 MB [384][1024]
    __bf16* Wpb   = (__bf16*)(ws + 128 * MB);   //  0.3 MB
    float*  Part  = (float*) (ws + 129 * MB);   //  4.2 MB
    __bf16* KtvTb = (__bf16*)(ws + 134 * MB);   //  32 KB
    __bf16* Ctxb  = (__bf16*)(ws + 135 * MB);   //  2.1 MB
    float*  bqkvf = (float*) (ws + 138 * MB);   //  1.5 KB

    const dim3 blk(256);

    // casts
    cast_f32_bf16<<<2048, blk, 0, stream>>>(x,  xb,           MROWS * DMODEL / 8);
    cast_f32_bf16<<<64,   blk, 0, stream>>>(Wq, Wqkvb,        DK * DMODEL / 8);
    cast_f32_bf16<<<64,   blk, 0, stream>>>(Wk, Wqkvb + DK * DMODEL,     DK * DMODEL / 8);
    cast_f32_bf16<<<64,   blk, 0, stream>>>(Wv, Wqkvb + 2 * DK * DMODEL, DK * DMODEL / 8);
    cast_f32_bf16<<<64,   blk, 0, stream>>>(Wp, Wpb,          DMODEL * DK / 8);
    cast_f32_bf16<<<1024, blk, 0, stream>>>(W1, W1b,          DFF * DMODEL / 8);
    cast_f32_bf16<<<1024, blk, 0, stream>>>(W2, W2b,          DMODEL * DFF / 8);
    pack_bias3<<<1, 128, 0, stream>>>(bq, bk, bv, bqkvf);

    // QKV packed projection -> bf16 [8192,384]
    gemm128<false,false,true,true,false><<<dim3(3, 64), blk, 0, stream>>>(
        xb, DMODEL, Wqkvb, bqkvf, nullptr, QKVb, nullptr, 3 * DK, DMODEL);

    // KtV (128x128) -> transposed bf16
    ktv_partial<<<64, blk, 0, stream>>>(QKVb + DK, QKVb + 2 * DK, 3 * DK, Part);
    ktv_reduce <<<64, blk, 0, stream>>>(Part, KtvTb);

    // context = Q @ KtV -> bf16 [8192,128]
    gemm128<false,false,false,true,false><<<dim3(1, 64), blk, 0, stream>>>(
        QKVb, 3 * DK, KtvTb, nullptr, nullptr, Ctxb, nullptr, DK, DK);

    // x2 = x + ctx @ Wp^T + bp -> fp32 d_out AND bf16 x2b (fused cast)
    gemm128<false,true,true,false,true><<<dim3(8, 64), blk, 0, stream>>>(
        Ctxb, DK, Wpb, bp, x, out, x2b, DMODEL, DK);

    // h = relu(x2 @ W1^T + b1) -> bf16 [8192,4096]; 32x16 = 512 blocks
    gemm256p<true,false,true,true><<<512, 512, 0, stream>>>(
        x2b, DMODEL, W1b, b1, nullptr, Hb, DFF, DMODEL, DFF / 256);

    // y = x2 + h @ W2^T + b2 -> fp32 d_out; 32x4 = 128 blocks
    gemm256p<false,true,true,false><<<128, 512, 0, stream>>>(
        Hb, DFF, W2b, b2, out, out, DMODEL, DFF, DMODEL / 256);
}

// Round 6
// 265.729 us; speedup vs baseline: 1.2017x; 1.1136x over previous
//
#include <hip/hip_runtime.h>

// LinearAttentionBlock bf16 MFMA. Attention reassociated: Q@(K'V).
// FFN GEMMs: m201 8-phase 256x256/BK=64 template, stage-early variant:
//   stage both B halves of tile t+2 at ph1, both A halves at ph3,
//   boundary vmcnt(8) (16 loads in flight, retires exactly tile t+1's 8).
// FFN2: split-K=2 in one 256-block launch (bf16 partials) + fused reduce.
// Round-5 bug fixed: P1 must equal P0 + MROWS*DMODEL (shard stride), it was
// at an unrelated +17MB offset -> reduce read garbage.
// Small GEMMs: m97-style 128x128 kernel (round-2 proven).

#define MROWS 8192
#define DMODEL 1024
#define DK 128
#define DFF 4096

typedef __attribute__((ext_vector_type(8))) __bf16 bf16x8;
typedef __attribute__((ext_vector_type(4))) float f32x4;

#define BAR()    asm volatile("s_barrier" ::: "memory")
#define WAITV(n) asm volatile("s_waitcnt vmcnt(" #n ")" ::: "memory")
#define GLOAD(src, dst) __builtin_amdgcn_global_load_lds( \
    (const __attribute__((address_space(1))) void*)(src), \
    (__attribute__((address_space(3))) void*)(dst), 16, 0, 0)

__global__ __launch_bounds__(256) void cast_f32_bf16(
    const float* __restrict__ src, __bf16* __restrict__ dst, int n8)
{
    for (int i = blockIdx.x * blockDim.x + threadIdx.x; i < n8;
         i += gridDim.x * blockDim.x) {
        const float4 a = reinterpret_cast<const float4*>(src)[2 * i];
        const float4 b = reinterpret_cast<const float4*>(src)[2 * i + 1];
        bf16x8 o;
        o[0] = (__bf16)a.x; o[1] = (__bf16)a.y; o[2] = (__bf16)a.z; o[3] = (__bf16)a.w;
        o[4] = (__bf16)b.x; o[5] = (__bf16)b.y; o[6] = (__bf16)b.z; o[7] = (__bf16)b.w;
        reinterpret_cast<bf16x8*>(dst)[i] = o;
    }
}

__global__ void pack_bias3(const float* __restrict__ a, const float* __restrict__ b,
                           const float* __restrict__ c, float* __restrict__ o)
{
    const int t = threadIdx.x;
    o[t] = a[t]; o[128 + t] = b[t]; o[256 + t] = c[t];
}

// y = x2 + P0 + P1 + b2   (all [8192][1024]; P bf16, rest fp32; in-place on y)
__global__ __launch_bounds__(256) void ffn2_reduce(
    float* __restrict__ y, const __bf16* __restrict__ P0,
    const __bf16* __restrict__ P1, const float* __restrict__ b2, int n8)
{
    for (int i = blockIdx.x * blockDim.x + threadIdx.x; i < n8;
         i += gridDim.x * blockDim.x) {
        const int col0 = (i << 3) & (DMODEL - 1);
        const float4 ba = *reinterpret_cast<const float4*>(&b2[col0]);
        const float4 bb = *reinterpret_cast<const float4*>(&b2[col0 + 4]);
        float4 o0 = reinterpret_cast<const float4*>(y)[2 * i];
        float4 o1 = reinterpret_cast<const float4*>(y)[2 * i + 1];
        const bf16x8 p0 = reinterpret_cast<const bf16x8*>(P0)[i];
        const bf16x8 p1 = reinterpret_cast<const bf16x8*>(P1)[i];
        o0.x += (float)p0[0] + (float)p1[0] + ba.x;
        o0.y += (float)p0[1] + (float)p1[1] + ba.y;
        o0.z += (float)p0[2] + (float)p1[2] + ba.z;
        o0.w += (float)p0[3] + (float)p1[3] + ba.w;
        o1.x += (float)p0[4] + (float)p1[4] + bb.x;
        o1.y += (float)p0[5] + (float)p1[5] + bb.y;
        o1.z += (float)p0[6] + (float)p1[6] + bb.z;
        o1.w += (float)p0[7] + (float)p1[7] + bb.w;
        reinterpret_cast<float4*>(y)[2 * i]     = o0;
        reinterpret_cast<float4*>(y)[2 * i + 1] = o1;
    }
}

// ---------------------------------------------------------------------------
// 128x128 m97-style GEMM (round-2 proven). DUAL adds a bf16 secondary output.
// ---------------------------------------------------------------------------
template<bool RELU, bool RESID, bool BIAS, bool OUTBF, bool DUAL>
__global__ __launch_bounds__(256) void gemm128(
    const __bf16* __restrict__ A, int lda,
    const __bf16* __restrict__ W,
    const float* __restrict__ bias,
    const float* __restrict__ resid,
    void* __restrict__ Cout, __bf16* __restrict__ Cbf, int ldc, int K)
{
    constexpr int BK = 32;
    __shared__ __bf16 As[128 * BK];
    __shared__ __bf16 Bs[128 * BK];

    const int tid  = threadIdx.x;
    const int lane = tid & 63;
    const int w    = tid >> 6;
    const int wm   = w >> 1;
    const int wn   = w & 1;
    const int fr   = lane & 15;
    const int fq   = lane >> 4;

    const long row0 = (long)blockIdx.y * 128;
    const long col0 = (long)blockIdx.x * 128;

    const int sr = (w << 4) + (lane >> 2);
    const int sc = (lane & 3) << 3;

    const __bf16* gA0 = A + (row0 + sr) * (long)lda + sc;
    const __bf16* gA1 = A + (row0 + 64 + sr) * (long)lda + sc;
    const __bf16* gW0 = W + (col0 + sr) * (long)K + sc;
    const __bf16* gW1 = W + (col0 + 64 + sr) * (long)K + sc;

    __bf16* lA0 = &As[(w << 4) * BK];
    __bf16* lA1 = &As[((w << 4) + 64) * BK];
    __bf16* lB0 = &Bs[(w << 4) * BK];
    __bf16* lB1 = &Bs[((w << 4) + 64) * BK];

    f32x4 acc[4][4] = {};

    for (int k0 = 0; k0 < K; k0 += BK) {
        GLOAD(gA0 + k0, lA0);
        GLOAD(gA1 + k0, lA1);
        GLOAD(gW0 + k0, lB0);
        GLOAD(gW1 + k0, lB1);
        __syncthreads();

        bf16x8 af[4], bfr[4];
        #pragma unroll
        for (int m = 0; m < 4; m++)
            af[m] = *reinterpret_cast<const bf16x8*>(
                &As[(wm * 64 + m * 16 + fr) * BK + fq * 8]);
        #pragma unroll
        for (int n = 0; n < 4; n++)
            bfr[n] = *reinterpret_cast<const bf16x8*>(
                &Bs[(wn * 64 + n * 16 + fr) * BK + fq * 8]);

        #pragma unroll
        for (int m = 0; m < 4; m++)
            #pragma unroll
            for (int n = 0; n < 4; n++)
                acc[m][n] = __builtin_amdgcn_mfma_f32_16x16x32_bf16(
                    af[m], bfr[n], acc[m][n], 0, 0, 0);
        __syncthreads();
    }

    #pragma unroll
    for (int n = 0; n < 4; n++) {
        const long c = col0 + wn * 64 + n * 16 + fr;
        float bc = 0.0f;
        if constexpr (BIAS) bc = bias[c];
        #pragma unroll
        for (int m = 0; m < 4; m++) {
            #pragma unroll
            for (int j = 0; j < 4; j++) {
                const long r = row0 + wm * 64 + m * 16 + fq * 4 + j;
                float v = acc[m][n][j];
                if constexpr (BIAS)  v += bc;
                if constexpr (RESID) v += resid[r * ldc + c];
                if constexpr (RELU)  v = fmaxf(v, 0.0f);
                if constexpr (OUTBF) ((__bf16*)Cout)[r * ldc + c] = (__bf16)v;
                else                 ((float*)Cout)[r * ldc + c] = v;
                if constexpr (DUAL)  Cbf[r * ldc + c] = (__bf16)v;
            }
        }
    }
}

// ---------------------------------------------------------------------------
// 8-phase 256x256 GEMM, BK=64, 512 thr = 8 waves (2M x 4N), per-wave 128x64.
// LDS = 8 half-slots x 16KB (slot(u&1,j): j 0=B0,1=B1,2=A0,3=A1).
// Stage-early: during tile t issue (t+2,B0/B1) at ph1 (B slots free after ph0)
// and (t+2,A0/A1) at ph3 (A slots free after ph2). Boundary vmcnt(8): 16 in
// flight, retires exactly tile t+1's 8 loads (~5-7 phases of slack).
// Split-K: grid = nshards*nb; shard sid=bid/nb offsets A,W by sid*klen and
// writes its own output (sid*sstride elems apart). klen%64==0, klen/64>=2.
// ---------------------------------------------------------------------------
template<bool RELU, bool RESID, bool BIAS, bool OUTBF>
__global__ __launch_bounds__(512, 2) void gemm256p(
    const __bf16* __restrict__ A, int lda,
    const __bf16* __restrict__ W, int ldw,
    const float* __restrict__ bias,
    const float* __restrict__ resid,
    void* __restrict__ Cout, long sstride, int ldc,
    int klen, int nb, int nbx)
{
    __shared__ char lds[8][16384];

    const int bid = blockIdx.x;
    const int sid = bid / nb;          // K-shard
    const int ib  = bid % nb;
    // T1: XCD-chunked bijective swizzle within shard (nb % 8 == 0)
    const int chunk = nb >> 3;
    const int swz   = (ib & 7) * chunk + (ib >> 3);
    const int bx    = swz % nbx;
    const int by    = swz / nbx;

    const long row0 = (long)by * 256;
    const long col0 = (long)bx * 256;

    const __bf16* Ash = A + (long)sid * klen;
    const __bf16* Wsh = W + (long)sid * klen;

    const int tid  = threadIdx.x;
    const int lane = tid & 63;
    const int w    = tid >> 6;    // wave 0..7
    const int wm   = w >> 2;      // 0..1  -> A-half
    const int wn   = w & 3;       // 0..3
    const int fr   = lane & 15;
    const int fq   = lane >> 4;   // 0..3

    // staging source (pre-swizzled col), rows = half*128 + w*8 + (lane>>3)
    const int srow8 = lane >> 3;                    // 0..7
    const int scole = ((lane & 7) ^ srow8) << 3;    // T2 pre-swizzled col
    const __bf16* gA = Ash + (row0 + w * 8 + srow8) * (long)lda + scole;
    const __bf16* gB = Wsh + (col0 + w * 8 + srow8) * (long)ldw + scole;

    char* ldsc = &lds[0][0];
    const int nt = klen >> 6;

    // stage half-tile j of K-tile u (j: 0=B0,1=B1,2=A0,3=A1); 2 loads/thread
    auto stage = [&](int u, int j) {
        if (u >= nt) return;
        char* dst = ldsc + (((u & 1) << 2 | j) << 14) + (w << 10);
        if (j < 2) {
            const __bf16* s = gB + ((long)j * 128) * (long)ldw + (long)u * 64;
            GLOAD(s, dst);
            GLOAD(s + 64 * (long)ldw, dst + 8192);
        } else {
            const __bf16* s = gA + ((long)(j - 2) * 128) * (long)lda + (long)u * 64;
            GLOAD(s, dst);
            GLOAD(s + 64 * (long)lda, dst + 8192);
        }
    };

    // reader lane bases within a half-slot; T2 swizzle byte ^= ((fr&7)<<4)
    const int rb0 = fr * 128 + ((fq * 16) ^ ((fr & 7) << 4));
    const int rb1 = fr * 128 + ((64 + fq * 16) ^ ((fr & 7) << 4));

    f32x4 acc[8][4] = {};

    // prologue: stage tiles 0 and 1 completely (16 loads); wait tile 0
    stage(0, 0); stage(0, 1); stage(0, 2); stage(0, 3);
    stage(1, 0); stage(1, 1); stage(1, 2); stage(1, 3);
    WAITV(8);
    BAR();

    for (int t = 0; t < nt; ++t) {
        const char* base = ldsc + ((t & 1) << 16);
        const char* pB = base + ((wn >> 1) << 14) + ((wn & 1) << 13);
        const char* pA = base + ((2 + wm) << 14);

        bf16x8 a[8][2], bb[4][2];

        // ---------- phase 0: read B (8) + A m0-1 (4); MFMA m0,m1
        #pragma unroll
        for (int n = 0; n < 4; n++) {
            bb[n][0] = *reinterpret_cast<const bf16x8*>(pB + rb0 + n * 2048);
            bb[n][1] = *reinterpret_cast<const bf16x8*>(pB + rb1 + n * 2048);
        }
        #pragma unroll
        for (int m = 0; m < 2; m++) {
            a[m][0] = *reinterpret_cast<const bf16x8*>(pA + rb0 + m * 2048);
            a[m][1] = *reinterpret_cast<const bf16x8*>(pA + rb1 + m * 2048);
        }
        BAR();
        __builtin_amdgcn_s_setprio(1);
        #pragma unroll
        for (int m = 0; m < 2; m++)
            #pragma unroll
            for (int n = 0; n < 4; n++) {
                acc[m][n] = __builtin_amdgcn_mfma_f32_16x16x32_bf16(
                    a[m][0], bb[n][0], acc[m][n], 0, 0, 0);
                acc[m][n] = __builtin_amdgcn_mfma_f32_16x16x32_bf16(
                    a[m][1], bb[n][1], acc[m][n], 0, 0, 0);
            }
        __builtin_amdgcn_s_setprio(0);
        BAR();

        // ---------- phase 1: read A m2-5 (8); stage (t+2) B0,B1; MFMA m2,m3
        #pragma unroll
        for (int m = 2; m < 6; m++) {
            a[m][0] = *reinterpret_cast<const bf16x8*>(pA + rb0 + m * 2048);
            a[m][1] = *reinterpret_cast<const bf16x8*>(pA + rb1 + m * 2048);
        }
        stage(t + 2, 0);
        stage(t + 2, 1);
        BAR();
        __builtin_amdgcn_s_setprio(1);
        #pragma unroll
        for (int m = 2; m < 4; m++)
            #pragma unroll
            for (int n = 0; n < 4; n++) {
                acc[m][n] = __builtin_amdgcn_mfma_f32_16x16x32_bf16(
                    a[m][0], bb[n][0], acc[m][n], 0, 0, 0);
                acc[m][n] = __builtin_amdgcn_mfma_f32_16x16x32_bf16(
                    a[m][1], bb[n][1], acc[m][n], 0, 0, 0);
            }
        __builtin_amdgcn_s_setprio(0);
        BAR();

        // ---------- phase 2: read A m6-7 (4); MFMA m4,m5
        #pragma unroll
        for (int m = 6; m < 8; m++) {
            a[m][0] = *reinterpret_cast<const bf16x8*>(pA + rb0 + m * 2048);
            a[m][1] = *reinterpret_cast<const bf16x8*>(pA + rb1 + m * 2048);
        }
        BAR();
        __builtin_amdgcn_s_setprio(1);
        #pragma unroll
        for (int m = 4; m < 6; m++)
            #pragma unroll
            for (int n = 0; n < 4; n++) {
                acc[m][n] = __builtin_amdgcn_mfma_f32_16x16x32_bf16(
                    a[m][0], bb[n][0], acc[m][n], 0, 0, 0);
                acc[m][n] = __builtin_amdgcn_mfma_f32_16x16x32_bf16(
                    a[m][1], bb[n][1], acc[m][n], 0, 0, 0);
            }
        __builtin_amdgcn_s_setprio(0);
        BAR();

        // ---------- phase 3: stage (t+2) A0,A1; MFMA m6,m7
        stage(t + 2, 2);
        stage(t + 2, 3);
        BAR();
        __builtin_amdgcn_s_setprio(1);
        #pragma unroll
        for (int m = 6; m < 8; m++)
            #pragma unroll
            for (int n = 0; n < 4; n++) {
                acc[m][n] = __builtin_amdgcn_mfma_f32_16x16x32_bf16(
                    a[m][0], bb[n][0], acc[m][n], 0, 0, 0);
                acc[m][n] = __builtin_amdgcn_mfma_f32_16x16x32_bf16(
                    a[m][1], bb[n][1], acc[m][n], 0, 0, 0);
            }
        __builtin_amdgcn_s_setprio(0);

        // ---------- boundary: retire exactly tile t+1's 8 loads
        if (t + 2 < nt)      { WAITV(8); }
        else if (t + 1 < nt) { WAITV(0); }
        BAR();
    }

    // epilogue: C/D layout col = lane&15, row = (lane>>4)*4 + reg
    __bf16* Cb = (__bf16*)Cout + (long)sid * sstride;
    float*  Cf = (float*)Cout;
    #pragma unroll
    for (int n = 0; n < 4; n++) {
        const long c = col0 + wn * 64 + n * 16 + fr;
        float bc = 0.0f;
        if constexpr (BIAS) bc = bias[c];
        #pragma unroll
        for (int m = 0; m < 8; m++) {
            #pragma unroll
            for (int j = 0; j < 4; j++) {
                const long r = row0 + wm * 128 + m * 16 + fq * 4 + j;
                float v = acc[m][n][j];
                if constexpr (BIAS)  v += bc;
                if constexpr (RESID) v += resid[r * ldc + c];
                if constexpr (RELU)  v = fmaxf(v, 0.0f);
                if constexpr (OUTBF) Cb[r * ldc + c] = (__bf16)v;
                else                 Cf[r * ldc + c] = v;
            }
        }
    }
}

// ---------------------------------------------------------------------------
// K^T @ V partials + reduce (round-2 proven)
// ---------------------------------------------------------------------------
__global__ __launch_bounds__(256) void ktv_partial(
    const __bf16* __restrict__ Kp, const __bf16* __restrict__ Vp,
    int ld, float* __restrict__ part)
{
    __shared__ float ks[32][DK];
    __shared__ float vs[32][DK];
    const int tid = threadIdx.x;
    const int ti  = tid >> 4;
    const int tj  = tid & 15;
    float acc[8][8] = {};
    const long base = (long)blockIdx.x * 128;

    for (int n0 = 0; n0 < 128; n0 += 32) {
        for (int t = tid; t < 512; t += 256) {
            const int r  = t >> 4;
            const int cc = (t & 15) << 3;
            const bf16x8 k8 = *reinterpret_cast<const bf16x8*>(
                &Kp[(base + n0 + r) * (long)ld + cc]);
            const bf16x8 v8 = *reinterpret_cast<const bf16x8*>(
                &Vp[(base + n0 + r) * (long)ld + cc]);
            #pragma unroll
            for (int u = 0; u < 8; u++) {
                ks[r][cc + u] = (float)k8[u];
                vs[r][cc + u] = (float)v8[u];
            }
        }
        __syncthreads();
        for (int n = 0; n < 32; n++) {
            float kk[8], vv[8];
            #pragma unroll
            for (int i = 0; i < 8; i++) kk[i] = ks[n][(ti << 3) + i];
            #pragma unroll
            for (int j = 0; j < 8; j++) vv[j] = vs[n][(tj << 3) + j];
            #pragma unroll
            for (int i = 0; i < 8; i++)
                #pragma unroll
                for (int j = 0; j < 8; j++)
                    acc[i][j] = fmaf(kk[i], vv[j], acc[i][j]);
        }
        __syncthreads();
    }

    float* dst = &part[(long)blockIdx.x * (DK * DK)];
    #pragma unroll
    for (int i = 0; i < 8; i++) {
        const int ig = (ti << 3) + i;
        *reinterpret_cast<float4*>(&dst[ig * DK + (tj << 3)]) =
            make_float4(acc[i][0], acc[i][1], acc[i][2], acc[i][3]);
        *reinterpret_cast<float4*>(&dst[ig * DK + (tj << 3) + 4]) =
            make_float4(acc[i][4], acc[i][5], acc[i][6], acc[i][7]);
    }
}

__global__ __launch_bounds__(256) void ktv_reduce(
    const float* __restrict__ part, __bf16* __restrict__ ktvT)
{
    const int t = blockIdx.x * 256 + threadIdx.x;
    const int i = t >> 7;
    const int j = t & 127;
    float s = 0.0f;
    for (int b = 0; b < 64; b++) s += part[(long)b * (DK * DK) + t];
    ktvT[j * DK + i] = (__bf16)s;
}

// ---------------------------------------------------------------------------
extern "C" void kernel_launch(void* const* d_in, const int* in_sizes, int n_in,
                              void* d_out, int out_size, void* d_ws, size_t ws_size,
                              hipStream_t stream) {
    const float* x  = (const float*)d_in[0];
    const float* Wq = (const float*)d_in[1];
    const float* bq = (const float*)d_in[2];
    const float* Wk = (const float*)d_in[3];
    const float* bk = (const float*)d_in[4];
    const float* Wv = (const float*)d_in[5];
    const float* bv = (const float*)d_in[6];
    const float* Wp = (const float*)d_in[7];
    const float* bp = (const float*)d_in[8];
    const float* W1 = (const float*)d_in[9];
    const float* b1 = (const float*)d_in[10];
    const float* W2 = (const float*)d_in[11];
    const float* b2 = (const float*)d_in[12];
    float* out = (float*)d_out;

    char* ws = (char*)d_ws;
    const size_t MB = 1ull << 20;
    // FFN2 split-K partials: P0 at ws, P1 = P0 + MROWS*DMODEL elems (16 MiB)
    // exactly matching the kernel's sid*sstride write offset. They reuse the
    // xb (dead after QKV) and part of x2b (dead after FFN1) regions.
    __bf16* xb    = (__bf16*)(ws);              // 16 MiB (dead after QKV)
    __bf16* P0    = (__bf16*)(ws);              // shard-0 partial
    __bf16* P1    = P0 + (long)MROWS * DMODEL;  // shard-1 partial (ws+16MiB)
    __bf16* x2b   = (__bf16*)(ws +  34 * MB);   // 16 MiB (dead after FFN1)
    __bf16* Hb    = (__bf16*)(ws +  51 * MB);   // 64 MiB
    __bf16* QKVb  = (__bf16*)(ws + 119 * MB);   //  6.3 MB [8192][384]
    __bf16* W1b   = (__bf16*)(ws + 126 * MB);   //  8.4 MB
    __bf16* W2b   = (__bf16*)(ws + 135 * MB);   //  8.4 MB
    __bf16* Wqkvb = (__bf16*)(ws + 144 * MB);   //  0.8 MB [384][1024]
    __bf16* Wpb   = (__bf16*)(ws + 145 * MB);   //  0.3 MB
    float*  Part  = (float*) (ws + 146 * MB);   //  4.2 MB
    __bf16* KtvTb = (__bf16*)(ws + 151 * MB);   //  32 KB
    __bf16* Ctxb  = (__bf16*)(ws + 152 * MB);   //  2.1 MB
    float*  bqkvf = (float*) (ws + 155 * MB);   //  1.5 KB

    const dim3 blk(256);

    // casts
    cast_f32_bf16<<<2048, blk, 0, stream>>>(x,  xb,           MROWS * DMODEL / 8);
    cast_f32_bf16<<<64,   blk, 0, stream>>>(Wq, Wqkvb,        DK * DMODEL / 8);
    cast_f32_bf16<<<64,   blk, 0, stream>>>(Wk, Wqkvb + DK * DMODEL,     DK * DMODEL / 8);
    cast_f32_bf16<<<64,   blk, 0, stream>>>(Wv, Wqkvb + 2 * DK * DMODEL, DK * DMODEL / 8);
    cast_f32_bf16<<<64,   blk, 0, stream>>>(Wp, Wpb,          DMODEL * DK / 8);
    cast_f32_bf16<<<1024, blk, 0, stream>>>(W1, W1b,          DFF * DMODEL / 8);
    cast_f32_bf16<<<1024, blk, 0, stream>>>(W2, W2b,          DMODEL * DFF / 8);
    pack_bias3<<<1, 128, 0, stream>>>(bq, bk, bv, bqkvf);

    // QKV packed projection -> bf16 [8192,384]
    gemm128<false,false,true,true,false><<<dim3(3, 64), blk, 0, stream>>>(
        xb, DMODEL, Wqkvb, bqkvf, nullptr, QKVb, nullptr, 3 * DK, DMODEL);

    // KtV (128x128) -> transposed bf16
    ktv_partial<<<64, blk, 0, stream>>>(QKVb + DK, QKVb + 2 * DK, 3 * DK, Part);
    ktv_reduce <<<64, blk, 0, stream>>>(Part, KtvTb);

    // context = Q @ KtV -> bf16 [8192,128]
    gemm128<false,false,false,true,false><<<dim3(1, 64), blk, 0, stream>>>(
        QKVb, 3 * DK, KtvTb, nullptr, nullptr, Ctxb, nullptr, DK, DK);

    // x2 = x + ctx @ Wp^T + bp -> fp32 d_out AND bf16 x2b (fused cast)
    gemm128<false,true,true,false,true><<<dim3(8, 64), blk, 0, stream>>>(
        Ctxb, DK, Wpb, bp, x, out, x2b, DMODEL, DK);

    // h = relu(x2 @ W1^T + b1) -> bf16 [8192,4096]; 512 blocks, no split
    gemm256p<true,false,true,true><<<512, 512, 0, stream>>>(
        x2b, DMODEL, W1b, DMODEL, b1, nullptr, Hb, 0, DFF,
        DMODEL, 512, DFF / 256);

    // FFN2 split-K=2: shard s computes H[:,s*2048:] @ W2[:,s*2048:]^T
    // -> bf16 partials P0,P1 [8192][1024]; 2 shards x 128 blocks = 256 blocks
    gemm256p<false,false,false,true><<<256, 512, 0, stream>>>(
        Hb, DFF, W2b, DFF, nullptr, nullptr, P0,
        (long)MROWS * DMODEL, DMODEL, DFF / 2, 128, DMODEL / 256);

    // y = x2 + P0 + P1 + b2 (in-place on d_out)
    ffn2_reduce<<<2048, blk, 0, stream>>>(out, P0, P1, b2, MROWS * DMODEL / 8);
}